// Round 4
// baseline (186.174 us; speedup 1.0000x reference)
//
#include <hip/hip_runtime.h>
#include <stdint.h>
#include <math.h>

#define TK 256
#define TT 256
#define DD 64
#define HH 256
#define PAD 68          // LDS row stride in floats (break 32-bank pattern; 16B aligned)
#define NTHREADS 512

// ---- exact JAX threefry2x32 (key = (0,42), 20 rounds) ----
// Canonical Random123/JAX round structure; KAT: threefry2x32(k=(0,0), x=(0,0))
// == (0x6b200159, 0x99ba4efe).
__device__ __forceinline__ uint32_t rotl32(uint32_t x, uint32_t d) {
  return (x << d) | (x >> (32u - d));
}

__device__ __forceinline__ uint2 threefry2x32(uint32_t x0, uint32_t x1) {
  const uint32_t ks0 = 0u, ks1 = 42u, ks2 = 0x1BD11BDAu ^ 0u ^ 42u; // 0x1BD11BF0
  x0 += ks0; x1 += ks1;
#define TFR(r) { x0 += x1; x1 = rotl32(x1, r); x1 ^= x0; }
  TFR(13u) TFR(15u) TFR(26u) TFR(6u)
  x0 += ks1; x1 += ks2 + 1u;
  TFR(17u) TFR(29u) TFR(16u) TFR(24u)
  x0 += ks2; x1 += ks0 + 2u;
  TFR(13u) TFR(15u) TFR(26u) TFR(6u)
  x0 += ks0; x1 += ks1 + 3u;
  TFR(17u) TFR(29u) TFR(16u) TFR(24u)
  x0 += ks1; x1 += ks2 + 4u;
  TFR(13u) TFR(15u) TFR(26u) TFR(6u)
  x0 += ks2; x1 += ks0 + 5u;
#undef TFR
  return make_uint2(x0, x1);
}

__global__ __launch_bounds__(NTHREADS) void ep_fused(
    const int*   __restrict__ pN,
    const int*   __restrict__ leaf,   // [K][T] int32
    const float* __restrict__ emb,    // [K][T][D]
    const float* __restrict__ W1,     // [2D][H]
    const float* __restrict__ b1,     // [H]
    const float* __restrict__ W2,     // [H][D]
    const float* __restrict__ b2,     // [D]
    float*       __restrict__ out)
{
  __shared__ float s_emb[TT * PAD];   // 69632 B
  __shared__ float s_sq[TT];
  __shared__ float s_rm[NTHREADS];
  __shared__ float s_rs[NTHREADS];
  __shared__ float s_rb[NTHREADS];
  __shared__ int   s_ri[NTHREADS];
  __shared__ float s_h[HH];
  __shared__ float s_e[DD];
  __shared__ int   s_onesw[8];
  __shared__ int   s_sel[2];
  __shared__ float s_lse;

  const int k   = blockIdx.x;
  const int tid = threadIdx.x;
  const int i   = tid & 255;             // row this thread owns
  const int jbase = (tid >> 8) * 128;    // which half of j-range

  const float* ek = emb + (size_t)k * (TT * DD);

  // stage emb_k into LDS (coalesced float4)
  for (int idx = tid; idx < TT * DD / 4; idx += NTHREADS) {
    float4 v = ((const float4*)ek)[idx];
    int f = idx << 2;
    int r = f >> 6, c = f & 63;
    *(float4*)&s_emb[r * PAD + c] = v;
  }
  __syncthreads();

  // sq[i] = sum(emb_i^2)
  if (tid < TT) {
    const float* row = &s_emb[tid * PAD];
    float acc = 0.f;
#pragma unroll
    for (int c = 0; c < DD; ++c) acc = fmaf(row[c], row[c], acc);
    s_sq[tid] = acc;
  }
  __syncthreads();

  // own row into registers
  float a[DD];
  {
    const float* row = &s_emb[i * PAD];
#pragma unroll
    for (int c = 0; c < DD; ++c) a[c] = row[c];
  }
  const float sqi = s_sq[i];

  // PARTITIONABLE threefry (modern JAX default): flat element p gets
  // 64-bit counter split (hi, lo) = (0, p); bind -> (b1, b2);
  // for bit_width==32 JAX returns b1 ^ b2 (NOT truncation of b1<<32|b2).
  const uint32_t pb = ((uint32_t)k << 16) | ((uint32_t)i << 8);

  float m = -3.402823466e38f, ss = 0.f;     // online logsumexp state
  float best = -3.402823466e38f; int bj = jbase;

  for (int j = jbase; j < jbase + 128; ++j) {
    const float4* b4p = (const float4*)&s_emb[j * PAD];   // LDS broadcast
    float d0 = 0.f, d1 = 0.f, d2a = 0.f, d3 = 0.f;
#pragma unroll
    for (int c4 = 0; c4 < 16; ++c4) {
      float4 b4 = b4p[c4];
      d0  = fmaf(a[c4 * 4 + 0], b4.x, d0);
      d1  = fmaf(a[c4 * 4 + 1], b4.y, d1);
      d2a = fmaf(a[c4 * 4 + 2], b4.z, d2a);
      d3  = fmaf(a[c4 * 4 + 3], b4.w, d3);
    }
    float dot = (d0 + d1) + (d2a + d3);
    float dsq = sqi + s_sq[j] - 2.0f * dot;
    float lw  = -sqrtf(fmaxf(dsq, 0.f));
    if (j != i) {
      // online LSE (branchy: rescale is rare once m stabilizes)
      if (lw <= m) {
        ss += __expf(lw - m);
      } else {
        ss = fmaf(ss, __expf(m - lw), 1.0f);
        m = lw;
      }
      // exact JAX gumbel, partitionable bit layout: b1 ^ b2
      uint2 r = threefry2x32(0u, pb + (uint32_t)j);
      uint32_t bits = r.x ^ r.y;
      float f = __uint_as_float((bits >> 9) | 0x3F800000u) - 1.0f;  // [0,1)
      float u = fmaxf(f, 1.1754943508222875e-38f);                  // minval=tiny
      float g = -logf(-logf(u));
      float sv = lw + g;
      if (sv > best) { best = sv; bj = j; }   // strict > keeps first occurrence
    }
  }

  s_rm[tid] = m; s_rs[tid] = ss; s_rb[tid] = best; s_ri[tid] = i * TT + bj;
  __syncthreads();
  for (int off = NTHREADS / 2; off > 0; off >>= 1) {
    if (tid < off) {
      float m1 = s_rm[tid],       s1 = s_rs[tid];
      float m2 = s_rm[tid + off], s2 = s_rs[tid + off];
      float nm = fmaxf(m1, m2);
      s_rm[tid] = nm;
      s_rs[tid] = s1 * __expf(m1 - nm) + s2 * __expf(m2 - nm);
      float b1v = s_rb[tid];       int i1v = s_ri[tid];
      float b2v = s_rb[tid + off]; int i2v = s_ri[tid + off];
      if (b2v > b1v || (b2v == b1v && i2v < i1v)) { s_rb[tid] = b2v; s_ri[tid] = i2v; }
    }
    __syncthreads();
  }

  if (tid == 0) {
    int flat = s_ri[0];
    s_sel[0] = flat >> 8;      // idx1
    s_sel[1] = flat & 255;     // idx2
    s_lse    = s_rm[0] + logf(s_rs[0]);
  }
  // count leaf_counts==1 via per-wave ballot
  {
    int lane = tid & 63, wv = tid >> 6;
    int isone = (tid < TT) ? ((leaf[k * TT + tid] == 1) ? 1 : 0) : 0;
    unsigned long long bal = __ballot(isone);
    if (lane == 0) s_onesw[wv] = __popcll(bal);
  }
  __syncthreads();

  const int i1 = s_sel[0], i2 = s_sel[1];
  const float* c1 = &s_emb[i1 * PAD];
  const float* c2 = &s_emb[i2 * PAD];

  // h = relu([c1,c2] @ W1 + b1); W1 reads are lane-coalesced
  if (tid < HH) {
    float h0 = 0.f, h1 = 0.f;
#pragma unroll 8
    for (int c = 0; c < DD; ++c) h0 = fmaf(c1[c], W1[c * HH + tid], h0);
#pragma unroll 8
    for (int c = 0; c < DD; ++c) h1 = fmaf(c2[c], W1[(DD + c) * HH + tid], h1);
    s_h[tid] = fmaxf(h0 + h1 + b1[tid], 0.f);
  }
  __syncthreads();

  // e = h @ W2 + b2
  if (tid < DD) {
    float acc = 0.f;
#pragma unroll 8
    for (int hh = 0; hh < HH; ++hh) acc = fmaf(s_h[hh], W2[hh * DD + tid], acc);
    float e = acc + b2[tid];
    s_e[tid] = e;
    out[1024 + k * DD + tid] = e;          // embedding_KxD
  }
  __syncthreads();

  // branch lengths: ||c - e|| via wave-0 butterfly
  if (tid < DD) {
    float dd1 = c1[tid] - s_e[tid];
    float dd2 = c2[tid] - s_e[tid];
    float q1 = dd1 * dd1, q2 = dd2 * dd2;
#pragma unroll
    for (int off = 32; off > 0; off >>= 1) {
      q1 += __shfl_xor(q1, off);
      q2 += __shfl_xor(q2, off);
    }
    if (tid == 0) {
      out[512 + k] = sqrtf(q1);            // branch1_K
      out[768 + k] = sqrtf(q2);            // branch2_K
    }
  }

  if (tid == 0) {
    // recompute logw at the selected pair
    float dot = 0.f;
#pragma unroll
    for (int c = 0; c < DD; ++c) dot = fmaf(c1[c], c2[c], dot);
    float dsq = s_sq[i1] + s_sq[i2] - 2.0f * dot;
    float lw  = -sqrtf(fmaxf(dsq, 0.f));
    out[0   + k] = (float)i1;              // idx1_K
    out[256 + k] = (float)i2;              // idx2_K
    out[17408 + k] = lw + 0.69314718055994531f - s_lse;   // log_v_plus_K
    int ones = s_onesw[0] + s_onesw[1] + s_onesw[2] + s_onesw[3] +
               s_onesw[4] + s_onesw[5] + s_onesw[6] + s_onesw[7];
    ones -= (leaf[k * TT + i1] == 1) ? 1 : 0;
    ones -= (leaf[k * TT + i2] == 1) ? 1 : 0;
    int vminus = pN[0] - ones;
    out[17664 + k] = logf((float)vminus);  // log_v_minus_K
  }
}

extern "C" void kernel_launch(void* const* d_in, const int* in_sizes, int n_in,
                              void* d_out, int out_size, void* d_ws, size_t ws_size,
                              hipStream_t stream) {
  const int*   pN   = (const int*)d_in[0];
  const int*   leaf = (const int*)d_in[1];
  const float* emb  = (const float*)d_in[2];
  // d_in[3] = "log" scalar, unused
  const float* W1   = (const float*)d_in[4];
  const float* b1   = (const float*)d_in[5];
  const float* W2   = (const float*)d_in[6];
  const float* b2   = (const float*)d_in[7];
  float* out = (float*)d_out;

  ep_fused<<<TK, NTHREADS, 0, stream>>>(pN, leaf, emb, W1, b1, W2, b2, out);
}

// Round 5
// 180.355 us; speedup vs baseline: 1.0323x; 1.0323x over previous
//
#include <hip/hip_runtime.h>
#include <stdint.h>
#include <math.h>

#define TK 256
#define TT 256
#define DD 64
#define HH 256
#define PAD 68          // LDS row stride in floats
#define NTHREADS 1024
#define JPT 64          // j's per thread

// ---- exact JAX threefry2x32 (key = (0,42), 20 rounds) ----
__device__ __forceinline__ uint32_t rotl32(uint32_t x, uint32_t d) {
  return (x << d) | (x >> (32u - d));
}

__device__ __forceinline__ uint2 threefry2x32(uint32_t x0, uint32_t x1) {
  const uint32_t ks0 = 0u, ks1 = 42u, ks2 = 0x1BD11BDAu ^ 0u ^ 42u; // 0x1BD11BF0
  x0 += ks0; x1 += ks1;
#define TFR(r) { x0 += x1; x1 = rotl32(x1, r); x1 ^= x0; }
  TFR(13u) TFR(15u) TFR(26u) TFR(6u)
  x0 += ks1; x1 += ks2 + 1u;
  TFR(17u) TFR(29u) TFR(16u) TFR(24u)
  x0 += ks2; x1 += ks0 + 2u;
  TFR(13u) TFR(15u) TFR(26u) TFR(6u)
  x0 += ks0; x1 += ks1 + 3u;
  TFR(17u) TFR(29u) TFR(16u) TFR(24u)
  x0 += ks1; x1 += ks2 + 4u;
  TFR(13u) TFR(15u) TFR(26u) TFR(6u)
  x0 += ks2; x1 += ks0 + 5u;
#undef TFR
  return make_uint2(x0, x1);
}

__global__ __launch_bounds__(NTHREADS) void ep_fused(
    const int*   __restrict__ pN,
    const int*   __restrict__ leaf,   // [K][T] int32
    const float* __restrict__ emb,    // [K][T][D]
    const float* __restrict__ W1,     // [2D][H]
    const float* __restrict__ b1,     // [H]
    const float* __restrict__ W2,     // [H][D]
    const float* __restrict__ b2,     // [D]
    float*       __restrict__ out)
{
  __shared__ float s_emb[TT * PAD];   // 69632 B
  __shared__ float s_sq[TT];
  __shared__ float s_wss[16];
  __shared__ float s_wb[16];
  __shared__ int   s_wi[16];
  __shared__ float s_h[HH];
  __shared__ float s_e[DD];
  __shared__ int   s_onesw[16];
  __shared__ int   s_sel[2];
  __shared__ float s_lse;

  const int k   = blockIdx.x;
  const int tid = threadIdx.x;
  const int i   = tid & 255;             // row this thread owns
  const int jbase = (tid >> 8) * JPT;    // quarter of j-range

  const float* ek = emb + (size_t)k * (TT * DD);

  // stage emb_k into LDS (coalesced float4)
  for (int idx = tid; idx < TT * DD / 4; idx += NTHREADS) {
    float4 v = ((const float4*)ek)[idx];
    int f = idx << 2;
    int r = f >> 6, c = f & 63;
    *(float4*)&s_emb[r * PAD + c] = v;
  }
  __syncthreads();

  // sq[i] = sum(emb_i^2)
  if (tid < TT) {
    const float* row = &s_emb[tid * PAD];
    float acc = 0.f;
#pragma unroll
    for (int c = 0; c < DD; ++c) acc = fmaf(row[c], row[c], acc);
    s_sq[tid] = acc;
  }
  __syncthreads();

  // own row into registers
  float a[DD];
  {
    const float* row = &s_emb[i * PAD];
#pragma unroll
    for (int c = 0; c < DD; ++c) a[c] = row[c];
  }
  const float sqi = s_sq[i];

  // PARTITIONABLE threefry: counter (0, p), bits = b1 ^ b2 (verified R4)
  const uint32_t pb = ((uint32_t)k << 16) | ((uint32_t)i << 8);

  // fixed-shift LSE (all logits <= 0, so m=0 is overflow-safe)
  float ss = 0.f;
  float best = -3.402823466e38f; int bj = jbase;

  for (int j = jbase; j < jbase + JPT; ++j) {
    const float4* b4p = (const float4*)&s_emb[j * PAD];   // LDS broadcast
    float d0 = 0.f, d1 = 0.f, d2a = 0.f, d3 = 0.f;
#pragma unroll
    for (int c4 = 0; c4 < 16; ++c4) {
      float4 b4 = b4p[c4];
      d0  = fmaf(a[c4 * 4 + 0], b4.x, d0);
      d1  = fmaf(a[c4 * 4 + 1], b4.y, d1);
      d2a = fmaf(a[c4 * 4 + 2], b4.z, d2a);
      d3  = fmaf(a[c4 * 4 + 3], b4.w, d3);
    }
    float dot = (d0 + d1) + (d2a + d3);
    float dsq = sqi + s_sq[j] - 2.0f * dot;
    float lw  = -sqrtf(fmaxf(dsq, 0.f));
    if (j != i) {
      ss += __expf(lw);
      // exact JAX gumbel bits; fast log for selection-only value
      uint2 r = threefry2x32(0u, pb + (uint32_t)j);
      uint32_t bits = r.x ^ r.y;
      float f = __uint_as_float((bits >> 9) | 0x3F800000u) - 1.0f;  // [0,1)
      float u = fmaxf(f, 1.1754943508222875e-38f);                  // minval=tiny
      float g = -__logf(-__logf(u));
      float sv = lw + g;
      if (sv > best) { best = sv; bj = j; }   // strict > keeps first occurrence
    }
  }

  // per-wave butterfly reductions (width 64)
  int bidx = i * TT + bj;
#pragma unroll
  for (int off = 32; off > 0; off >>= 1) {
    ss += __shfl_xor(ss, off);
    float ob = __shfl_xor(best, off);
    int   oi = __shfl_xor(bidx, off);
    if (ob > best || (ob == best && oi < bidx)) { best = ob; bidx = oi; }
  }
  {
    int lane = tid & 63, wv = tid >> 6;
    if (lane == 0) { s_wss[wv] = ss; s_wb[wv] = best; s_wi[wv] = bidx; }
  }
  // count leaf_counts==1 via per-wave ballot
  {
    int lane = tid & 63, wv = tid >> 6;
    int isone = (tid < TT) ? ((leaf[k * TT + tid] == 1) ? 1 : 0) : 0;
    unsigned long long bal = __ballot(isone);
    if (lane == 0) s_onesw[wv] = __popcll(bal);
  }
  __syncthreads();

  if (tid == 0) {
    float tot = 0.f, bb = -3.402823466e38f; int bi = 0x7fffffff;
    for (int w = 0; w < 16; ++w) {
      tot += s_wss[w];
      if (s_wb[w] > bb || (s_wb[w] == bb && s_wi[w] < bi)) { bb = s_wb[w]; bi = s_wi[w]; }
    }
    s_sel[0] = bi >> 8;       // idx1
    s_sel[1] = bi & 255;      // idx2
    s_lse    = logf(tot);     // accurate log, once
  }
  __syncthreads();

  const int i1 = s_sel[0], i2 = s_sel[1];
  const float* c1 = &s_emb[i1 * PAD];
  const float* c2 = &s_emb[i2 * PAD];

  // h = relu([c1,c2] @ W1 + b1); W1 reads are lane-coalesced
  if (tid < HH) {
    float h0 = 0.f, h1 = 0.f;
#pragma unroll 8
    for (int c = 0; c < DD; ++c) h0 = fmaf(c1[c], W1[c * HH + tid], h0);
#pragma unroll 8
    for (int c = 0; c < DD; ++c) h1 = fmaf(c2[c], W1[(DD + c) * HH + tid], h1);
    s_h[tid] = fmaxf(h0 + h1 + b1[tid], 0.f);
  }
  __syncthreads();

  // e = h @ W2 + b2
  if (tid < DD) {
    float acc = 0.f;
#pragma unroll 8
    for (int hh = 0; hh < HH; ++hh) acc = fmaf(s_h[hh], W2[hh * DD + tid], acc);
    float e = acc + b2[tid];
    s_e[tid] = e;
    out[1024 + k * DD + tid] = e;          // embedding_KxD
  }
  __syncthreads();

  // branch lengths: ||c - e|| via wave-0 butterfly
  if (tid < DD) {
    float dd1 = c1[tid] - s_e[tid];
    float dd2 = c2[tid] - s_e[tid];
    float q1 = dd1 * dd1, q2 = dd2 * dd2;
#pragma unroll
    for (int off = 32; off > 0; off >>= 1) {
      q1 += __shfl_xor(q1, off);
      q2 += __shfl_xor(q2, off);
    }
    if (tid == 0) {
      out[512 + k] = sqrtf(q1);            // branch1_K
      out[768 + k] = sqrtf(q2);            // branch2_K
    }
  }

  if (tid == 0) {
    // recompute logw at the selected pair
    float dot = 0.f;
#pragma unroll
    for (int c = 0; c < DD; ++c) dot = fmaf(c1[c], c2[c], dot);
    float dsq = s_sq[i1] + s_sq[i2] - 2.0f * dot;
    float lw  = -sqrtf(fmaxf(dsq, 0.f));
    out[0   + k] = (float)i1;              // idx1_K
    out[256 + k] = (float)i2;              // idx2_K
    out[17408 + k] = lw + 0.69314718055994531f - s_lse;   // log_v_plus_K
    int ones = 0;
    for (int w = 0; w < 16; ++w) ones += s_onesw[w];
    ones -= (leaf[k * TT + i1] == 1) ? 1 : 0;
    ones -= (leaf[k * TT + i2] == 1) ? 1 : 0;
    int vminus = pN[0] - ones;
    out[17664 + k] = logf((float)vminus);  // log_v_minus_K
  }
}

extern "C" void kernel_launch(void* const* d_in, const int* in_sizes, int n_in,
                              void* d_out, int out_size, void* d_ws, size_t ws_size,
                              hipStream_t stream) {
  const int*   pN   = (const int*)d_in[0];
  const int*   leaf = (const int*)d_in[1];
  const float* emb  = (const float*)d_in[2];
  // d_in[3] = "log" scalar, unused
  const float* W1   = (const float*)d_in[4];
  const float* b1   = (const float*)d_in[5];
  const float* W2   = (const float*)d_in[6];
  const float* b2   = (const float*)d_in[7];
  float* out = (float*)d_out;

  ep_fused<<<TK, NTHREADS, 0, stream>>>(pN, leaf, emb, W1, b1, W2, b2, out);
}